// Round 3
// baseline (1013.233 us; speedup 1.0000x reference)
//
#include <hip/hip_runtime.h>

// PoolAggregator fused, MFMA bf16 version, round 3.
//  k1: x = neigh@Wt + bt; per-node max/min over k (packed bf16 pair -> pmm) + BN1 sums.
//      Persistent 512 blocks x 512 thr; wave = 64 rows x 32 cols; A single-buffered LDS;
//      Wt B-frags gathered once per block from global (L2-resident).
//  k_stats: slot-reduce -> BN affine (a,c).  pool(BN(x)) = a>=0 ? a*max+c : a*min+c.
//  k2: [self@Ws | pooled@Wn]: 8 waves x 32 cols (waves 0-3 self K=128, 4-7 pooled K=256),
//      BN1 affine fused into Ap staging; writes pre-BN Y to d_out + BN2 sums. No spills.
//  k7: out = relu(a2*Y + c2) in place.

#define NN 50000
#define KN 25
#define FIN 128
#define TD 256
#define OUTD 128
#define BN_EPS 1e-3f
#define NSLOTS 64
#define K1_GRID 512
#define NGROUPS (NN / 2)

typedef float f32x4 __attribute__((ext_vector_type(4)));
typedef short bf16x8 __attribute__((ext_vector_type(8)));

__device__ __forceinline__ ushort f2bf(float f) {
    uint u = __builtin_bit_cast(uint, f);
    return (ushort)((u + 0x7FFFu + ((u >> 16) & 1u)) >> 16);
}
__device__ __forceinline__ uint pk2(float a, float b) {
    return (uint)f2bf(a) | ((uint)f2bf(b) << 16);
}
__device__ __forceinline__ float bf2f(ushort s) {
    return __builtin_bit_cast(float, (uint)s << 16);
}

// ============ K1: GEMM1 + pool-prep + BN1 stats ============
// Group = 2 nodes = 50 rows padded to 64 (node gi at rows 32gi..; rows 25-31 garbage,
// masked in epilogue — MFMA rows are independent so garbage can't leak).
__global__ __launch_bounds__(512, 4) void k1_gemm_pool(
    const float* __restrict__ neigh, const float* __restrict__ Wt,
    const float* __restrict__ bt, uint* __restrict__ pmm,
    float* __restrict__ s1sum, float* __restrict__ s1sq)
{
    __shared__ ushort Ash[64 * 136];   // 17408 B, single buffer
    const int tid = threadIdx.x;
    const int wave = tid >> 6, lane = tid & 63;
    const int quad = lane >> 4, l16 = lane & 15;
    const int cb = wave * 32;          // this wave's 32 output columns

    // ---- B-frags once, direct from global (Wt is 128 KB, L2-resident) ----
    bf16x8 bf[2][4];
    #pragma unroll
    for (int nt = 0; nt < 2; ++nt) {
        const int col = cb + nt * 16 + l16;
        #pragma unroll
        for (int ks = 0; ks < 4; ++ks)
            #pragma unroll
            for (int j = 0; j < 8; ++j)
                bf[nt][ks][j] = (short)f2bf(Wt[(size_t)(ks * 32 + quad * 8 + j) * TD + col]);
    }
    float bv[2];
    #pragma unroll
    for (int nt = 0; nt < 2; ++nt) bv[nt] = bt[cb + nt * 16 + l16];

    float S[2] = {0.f, 0.f}, Q[2] = {0.f, 0.f};

    for (int g = blockIdx.x; g < NGROUPS; g += K1_GRID) {
        // ---- stage A: 2 nodes = 3200 float2, f32 -> bf16 pack ----
        const float2* src = (const float2*)(neigh + (size_t)g * 6400);
        #pragma unroll
        for (int i = 0; i < 7; ++i) {
            const int idx = tid + i * 512;
            if (idx < 3200) {
                const float2 v = src[idx];
                const int r = idx >> 6;
                const int pr = r + (r >= 25 ? 7 : 0);   // node1 -> rows 32..56
                *(uint*)&Ash[pr * 136 + ((idx & 63) << 1)] = pk2(v.x, v.y);
            }
        }
        __syncthreads();

        // ---- MFMA: 4 m-tiles x 2 n-tiles x 4 k-slices ----
        f32x4 acc[4][2];
        #pragma unroll
        for (int m = 0; m < 4; ++m) { acc[m][0] = (f32x4){0,0,0,0}; acc[m][1] = (f32x4){0,0,0,0}; }
        #pragma unroll
        for (int m = 0; m < 4; ++m) {
            bf16x8 af[4];
            #pragma unroll
            for (int ks = 0; ks < 4; ++ks)
                af[ks] = *(const bf16x8*)&Ash[(m * 16 + l16) * 136 + ks * 32 + quad * 8];
            #pragma unroll
            for (int nt = 0; nt < 2; ++nt)
                #pragma unroll
                for (int ks = 0; ks < 4; ++ks)
                    acc[m][nt] = __builtin_amdgcn_mfma_f32_16x16x32_bf16(af[ks], bf[nt][ks], acc[m][nt], 0, 0, 0);
        }

        // ---- epilogue: node gi = m-tiles {2gi, 2gi+1}; C: col=lane&15, row=quad*4+i ----
        #pragma unroll
        for (int gi = 0; gi < 2; ++gi) {
            #pragma unroll
            for (int nt = 0; nt < 2; ++nt) {
                float mx = -3.4e38f, mn = 3.4e38f;
                #pragma unroll
                for (int i = 0; i < 4; ++i) {           // rows 0-15: all real
                    const float v = acc[2 * gi][nt][i] + bv[nt];
                    mx = fmaxf(mx, v); mn = fminf(mn, v);
                    S[nt] += v; Q[nt] = fmaf(v, v, Q[nt]);
                }
                #pragma unroll
                for (int i = 0; i < 4; ++i) {           // rows 16-31: valid iff quad*4+i<9
                    if (quad * 4 + i < 9) {
                        const float v = acc[2 * gi + 1][nt][i] + bv[nt];
                        mx = fmaxf(mx, v); mn = fminf(mn, v);
                        S[nt] += v; Q[nt] = fmaf(v, v, Q[nt]);
                    }
                }
                mx = fmaxf(mx, __shfl_xor(mx, 16)); mx = fmaxf(mx, __shfl_xor(mx, 32));
                mn = fminf(mn, __shfl_xor(mn, 16)); mn = fminf(mn, __shfl_xor(mn, 32));
                if (lane < 16)
                    pmm[(size_t)(g * 2 + gi) * TD + cb + nt * 16 + lane] = pk2(mx, mn);
            }
        }
        __syncthreads();   // before next stage overwrites Ash
    }

    // ---- flush BN1 stats once per block ----
    #pragma unroll
    for (int nt = 0; nt < 2; ++nt) {
        float s = S[nt]; s += __shfl_xor(s, 16); s += __shfl_xor(s, 32);
        float q = Q[nt]; q += __shfl_xor(q, 16); q += __shfl_xor(q, 32);
        if (lane < 16) {
            const int col = cb + nt * 16 + lane;
            const int slot = blockIdx.x & (NSLOTS - 1);
            atomicAdd(&s1sum[slot * TD + col], s);
            atomicAdd(&s1sq[slot * TD + col], q);
        }
    }
}

// ============ slot stats -> BN affine coefficients ============
__global__ __launch_bounds__(256) void k_stats(
    const float* __restrict__ ssum, const float* __restrict__ ssq,
    const float* __restrict__ g, const float* __restrict__ b,
    float invM, float* __restrict__ a, float* __restrict__ cc)
{
    const int c = threadIdx.x;
    float s = 0.f, q = 0.f;
    for (int j = 0; j < NSLOTS; ++j) { s += ssum[j * TD + c]; q += ssq[j * TD + c]; }
    const float mean = s * invM;
    const float var = q * invM - mean * mean;
    const float A = rsqrtf(var + BN_EPS) * g[c];
    a[c] = A;
    cc[c] = fmaf(-mean, A, b[c]);
}

// ============ K2: [self@Ws | pooled@Wn] -> pre-BN Y (d_out) + BN2 stats ============
// 512 thr / 8 waves per 64-row tile. Waves 0-3: self (K=128), waves 4-7: pooled (K=256).
__global__ __launch_bounds__(512, 2) void k2_gemm2(
    const float* __restrict__ selfn, const uint* __restrict__ pmm,
    const float* __restrict__ Ws, const float* __restrict__ Wn,
    const float* __restrict__ a1, const float* __restrict__ c1,
    float* __restrict__ Y, float* __restrict__ s2sum, float* __restrict__ s2sq)
{
    __shared__ ushort As[64 * 136];    // 17408 B
    __shared__ ushort Ap[64 * 264];    // 33792 B  (total 51200 B)
    const int tid = threadIdx.x;
    const int wave = tid >> 6, lane = tid & 63;
    const int quad = lane >> 4, l16 = lane & 15;
    const int R0 = blockIdx.x * 64;

    // ---- stage self -> As (bf16) ----
    {
        const float2* s2v = (const float2*)selfn;
        #pragma unroll
        for (int i = 0; i < 8; ++i) {
            const int e = tid + i * 512;           // < 4096
            const int r = e >> 6, c2 = e & 63;
            const int gr = R0 + r;
            const float2 v = (gr < NN) ? s2v[(size_t)gr * 64 + c2] : make_float2(0.f, 0.f);
            *(uint*)&As[r * 136 + (c2 << 1)] = pk2(v.x, v.y);
        }
    }
    // ---- stage pooled -> Ap: unpack max/min, BN1 affine + sign-select, to bf16 ----
    {
        #pragma unroll
        for (int i = 0; i < 32; ++i) {
            const int e = tid + i * 512;           // < 16384
            const int r = e >> 8, c = e & 255;
            const int gr = R0 + r;
            const uint u = (gr < NN) ? pmm[(size_t)gr * TD + c] : 0u;
            const float mx = bf2f((ushort)(u & 0xFFFFu));
            const float mn = bf2f((ushort)(u >> 16));
            const float a = a1[c], C = c1[c];
            const float p = (a >= 0.f) ? fmaf(a, mx, C) : fmaf(a, mn, C);
            Ap[r * 264 + c] = f2bf(p);
        }
    }
    __syncthreads();

    f32x4 acc[4][2];
    #pragma unroll
    for (int m = 0; m < 4; ++m) { acc[m][0] = (f32x4){0,0,0,0}; acc[m][1] = (f32x4){0,0,0,0}; }

    int colb;
    if (wave < 4) {
        colb = wave * 32;
        bf16x8 bfr[2][4];
        #pragma unroll
        for (int nt = 0; nt < 2; ++nt)
            #pragma unroll
            for (int ks = 0; ks < 4; ++ks)
                #pragma unroll
                for (int j = 0; j < 8; ++j)
                    bfr[nt][ks][j] = (short)f2bf(Ws[(size_t)(ks * 32 + quad * 8 + j) * OUTD + colb + nt * 16 + l16]);
        #pragma unroll
        for (int m = 0; m < 4; ++m) {
            bf16x8 af[4];
            #pragma unroll
            for (int ks = 0; ks < 4; ++ks)
                af[ks] = *(const bf16x8*)&As[(m * 16 + l16) * 136 + ks * 32 + quad * 8];
            #pragma unroll
            for (int nt = 0; nt < 2; ++nt)
                #pragma unroll
                for (int ks = 0; ks < 4; ++ks)
                    acc[m][nt] = __builtin_amdgcn_mfma_f32_16x16x32_bf16(af[ks], bfr[nt][ks], acc[m][nt], 0, 0, 0);
        }
    } else {
        const int cw = (wave - 4) * 32;
        colb = OUTD + cw;
        bf16x8 bfr[2][8];
        #pragma unroll
        for (int nt = 0; nt < 2; ++nt)
            #pragma unroll
            for (int ks = 0; ks < 8; ++ks)
                #pragma unroll
                for (int j = 0; j < 8; ++j)
                    bfr[nt][ks][j] = (short)f2bf(Wn[(size_t)(ks * 32 + quad * 8 + j) * OUTD + cw + nt * 16 + l16]);
        #pragma unroll
        for (int m = 0; m < 4; ++m) {
            bf16x8 af[8];
            #pragma unroll
            for (int ks = 0; ks < 8; ++ks)
                af[ks] = *(const bf16x8*)&Ap[(m * 16 + l16) * 264 + ks * 32 + quad * 8];
            #pragma unroll
            for (int nt = 0; nt < 2; ++nt)
                #pragma unroll
                for (int ks = 0; ks < 8; ++ks)
                    acc[m][nt] = __builtin_amdgcn_mfma_f32_16x16x32_bf16(af[ks], bfr[nt][ks], acc[m][nt], 0, 0, 0);
        }
    }

    // ---- epilogue: pre-BN Y + BN2 column stats ----
    float S[2] = {0.f, 0.f}, Q[2] = {0.f, 0.f};
    #pragma unroll
    for (int m = 0; m < 4; ++m) {
        #pragma unroll
        for (int nt = 0; nt < 2; ++nt) {
            #pragma unroll
            for (int i = 0; i < 4; ++i) {
                const int row = R0 + m * 16 + quad * 4 + i;
                if (row < NN) {
                    const float v = acc[m][nt][i];
                    Y[(size_t)row * TD + colb + nt * 16 + l16] = v;
                    S[nt] += v;
                    Q[nt] = fmaf(v, v, Q[nt]);
                }
            }
        }
    }
    #pragma unroll
    for (int nt = 0; nt < 2; ++nt) {
        float s = S[nt]; s += __shfl_xor(s, 16); s += __shfl_xor(s, 32);
        float q = Q[nt]; q += __shfl_xor(q, 16); q += __shfl_xor(q, 32);
        if (lane < 16) {
            const int col = colb + nt * 16 + lane;
            const int slot = blockIdx.x & (NSLOTS - 1);
            atomicAdd(&s2sum[slot * TD + col], s);
            atomicAdd(&s2sq[slot * TD + col], q);
        }
    }
}

// ============ K7: out = relu(a2*Y + c2) in place ============
__global__ __launch_bounds__(256) void k7_bn_relu(
    float* __restrict__ out, const float* __restrict__ a2, const float* __restrict__ c2)
{
    const int idx = blockIdx.x * 256 + threadIdx.x;   // float4 index over N*TD/4
    const int c4 = idx & 63;
    float4 y = ((const float4*)out)[idx];
    const float4 a = ((const float4*)a2)[c4];
    const float4 c = ((const float4*)c2)[c4];
    y.x = fmaxf(0.f, fmaf(a.x, y.x, c.x));
    y.y = fmaxf(0.f, fmaf(a.y, y.y, c.y));
    y.z = fmaxf(0.f, fmaf(a.z, y.z, c.z));
    y.w = fmaxf(0.f, fmaf(a.w, y.w, c.w));
    ((float4*)out)[idx] = y;
}

extern "C" void kernel_launch(void* const* d_in, const int* in_sizes, int n_in,
                              void* d_out, int out_size, void* d_ws, size_t ws_size,
                              hipStream_t stream) {
    const float* selfn = (const float*)d_in[0];
    const float* neigh = (const float*)d_in[1];
    // d_in[2] = len_adj_nodes: unused by the reference
    const float* Wt = (const float*)d_in[3];
    const float* bt = (const float*)d_in[4];
    const float* g1 = (const float*)d_in[5];
    const float* b1 = (const float*)d_in[6];
    const float* Wn = (const float*)d_in[7];
    const float* Ws = (const float*)d_in[8];
    const float* g2 = (const float*)d_in[9];
    const float* b2 = (const float*)d_in[10];
    float* out = (float*)d_out;

    // ws layout: pmm[N*T] uint | s1sum,s1sq,s2sum,s2sq [64*T f32 each] | a1,c1,a2,c2
    uint* pmm = (uint*)d_ws;
    float* s1sum = (float*)d_ws + (size_t)NN * TD;
    float* s1sq = s1sum + NSLOTS * TD;
    float* s2sum = s1sq + NSLOTS * TD;
    float* s2sq = s2sum + NSLOTS * TD;
    float* a1 = s2sq + NSLOTS * TD;
    float* c1 = a1 + TD;
    float* a2 = c1 + TD;
    float* c2 = a2 + TD;

    hipMemsetAsync(s1sum, 0, (size_t)4 * NSLOTS * TD * sizeof(float), stream);

    k1_gemm_pool<<<K1_GRID, 512, 0, stream>>>(neigh, Wt, bt, pmm, s1sum, s1sq);
    k_stats<<<1, 256, 0, stream>>>(s1sum, s1sq, g1, b1, 1.f / (float)(NN * KN), a1, c1);
    k2_gemm2<<<(NN + 63) / 64, 512, 0, stream>>>(selfn, pmm, Ws, Wn, a1, c1, out, s2sum, s2sq);
    k_stats<<<1, 256, 0, stream>>>(s2sum, s2sq, g2, b2, 1.f / (float)NN, a2, c2);
    k7_bn_relu<<<NN * TD / 4 / 256, 256, 0, stream>>>(out, a2, c2);
}